// Round 8
// baseline (78.946 us; speedup 1.0000x reference)
//
#include <hip/hip_runtime.h>

// Problem constants: B=2, C=32, H=128, W=256, maxdisp=12 -> D=23, shift = di-11
#define BB 2
#define CC 32
#define HH 128
#define WW 256
#define DD 23
#define HW (HH * WW)

#define SEG 128           // pixels per block (W split 2 ways)  [R8 single change]
#define NSEG 2
#define NCOLS 215         // staged cols: [128s-75 .. 128s+139] (128 + 87)
#define SC 36             // col stride in dwords (144 B, 16B-aligned)
#define SLAB (SEG * DD)   // 2944 floats per combine slab (stride 23, coprime 32)
#define SMEMN 8832        // max(215*36 = 7740 staging, 3*2944 = 8832 slabs)

// History: R3 structure = fast baseline (77.4). R7 proved occupancy-insensitive
// (16 vs 32 waves/CU neutral). R8 single change: halo redundancy 2.36x -> 1.68x
// (SEG 64 -> 128), cutting total HBM bytes ~17%. All else R3/R7-proven.

__global__ __launch_bounds__(512, 4) void cost_volume_kernel(
    const float* __restrict__ feat_l,
    const float* __restrict__ feat_r,
    const float* __restrict__ disp,
    float* __restrict__ out)
{
    __shared__ __align__(16) float smem[SMEMN];   // 35328 B -> 2 blocks/CU

    const int t  = threadIdx.x;          // 0..511
    const int q  = t >> 7;               // channel-octet group 0..3 (c0 = 8q)
    const int px = t & 127;              // pixel within segment
    const int s  = blockIdx.x >> 8;      // grid = NSEG*256
    const int bh = blockIdx.x & 255;
    const int b  = bh >> 7;
    const int h  = bh & 127;
    const int w  = s * SEG + px;
    const int COL0 = s * SEG - 75;
    const int c0 = q * 8;

    // ---- early independent global loads (R3-proven order: feat_l first) ----
    float fl[8];
    const size_t lbase = ((size_t)(b * CC + c0)) * HW + (size_t)h * WW + w;
    #pragma unroll
    for (int k = 0; k < 8; ++k) fl[k] = feat_l[lbase + (size_t)k * HW];
    const float d = disp[(size_t)bh * WW + w];

    // ---- stage feat_r window, channel-interleaved, b128 LDS writes ----
    {
        const int lane = t & 63;
        const int wid  = t >> 6;          // 0..7 -> channel quad cq = 4*wid
        const int cq   = wid * 4;
        #pragma unroll
        for (int cc = 0; cc < 4; ++cc) {  // 4*64 = 256 >= NCOLS
            const int col = cc * 64 + lane;
            if (col < NCOLS) {
                const int  gcol = col + COL0;
                const bool inr  = (gcol >= 0) && (gcol < WW);
                const int  gc   = min(max(gcol, 0), WW - 1);   // safe address
                const size_t base = ((size_t)(b * CC + cq)) * HW + (size_t)h * WW + gc;
                const float x0 = feat_r[base];
                const float x1 = feat_r[base + HW];
                const float x2 = feat_r[base + 2 * HW];
                const float x3 = feat_r[base + 3 * HW];
                float4 v;
                v.x = inr ? x0 : 0.0f;
                v.y = inr ? x1 : 0.0f;
                v.z = inr ? x2 : 0.0f;
                v.w = inr ? x3 : 0.0f;
                *(float4*)&smem[col * SC + cq] = v;
            }
        }
    }
    __syncthreads();

    // ---- per-pixel interp setup (shared across all di) ----
    const float pxf = (float)w - d;
    const float x0f = floorf(pxf);
    const float w1  = pxf - x0f;          // right-neighbor weight
    const float w0  = 1.0f - w1;
    int lb = (int)x0f - COL0 - 11;        // local col of tap j=0; in [px, px+64]
    lb = min(max(lb, 0), NCOLS - 24);     // no-op for disp in [0,64)

    // ---- 24-tap window, prefetch distance 2, 8 channels per thread ----
    float4 Ta[3], Tb[3];
    #define LOADTAP(idx, j) { \
        const float4* p_ = (const float4*)&smem[(lb + (j)) * SC + c0]; \
        Ta[idx] = p_[0]; Tb[idx] = p_[1]; }

    LOADTAP(0, 0)
    LOADTAP(1, 1)

    float acc[DD];
    #pragma unroll
    for (int di = 0; di < DD; ++di) {
        if (di + 2 < 24) LOADTAP((di + 2) % 3, di + 2)
        const float4 A0 = Ta[di % 3],       A1 = Tb[di % 3];
        const float4 B0 = Ta[(di + 1) % 3], B1 = Tb[(di + 1) % 3];
        float sA = 0.0f, sB = 0.0f;
        sA += fabsf(fmaf(w0, A0.x, fmaf(w1, B0.x, -fl[0])));
        sB += fabsf(fmaf(w0, A0.y, fmaf(w1, B0.y, -fl[1])));
        sA += fabsf(fmaf(w0, A0.z, fmaf(w1, B0.z, -fl[2])));
        sB += fabsf(fmaf(w0, A0.w, fmaf(w1, B0.w, -fl[3])));
        sA += fabsf(fmaf(w0, A1.x, fmaf(w1, B1.x, -fl[4])));
        sB += fabsf(fmaf(w0, A1.y, fmaf(w1, B1.y, -fl[5])));
        sA += fabsf(fmaf(w0, A1.z, fmaf(w1, B1.z, -fl[6])));
        sB += fabsf(fmaf(w0, A1.w, fmaf(w1, B1.w, -fl[7])));
        acc[di] = sA + sB;
    }
    #undef LOADTAP

    // ---- cross-group channel combine (reuse smem; stride 23 = conflict-free) ----
    __syncthreads();                       // all tap reads done before overwrite
    if (q != 0) {
        float* r = &smem[(q - 1) * SLAB + px * DD];
        #pragma unroll
        for (int di = 0; di < DD; ++di) r[di] = acc[di];
    }
    __syncthreads();
    if (q == 0) {
        const float* r0 = &smem[0 * SLAB + px * DD];
        const float* r1 = &smem[1 * SLAB + px * DD];
        const float* r2 = &smem[2 * SLAB + px * DD];
        #pragma unroll
        for (int di = 0; di < DD; ++di) {
            const float v = acc[di] + r0[di] + r1[di] + r2[di];
            out[((size_t)(b * DD + di)) * HW + (size_t)h * WW + w] = v;
        }
    }
}

extern "C" void kernel_launch(void* const* d_in, const int* in_sizes, int n_in,
                              void* d_out, int out_size, void* d_ws, size_t ws_size,
                              hipStream_t stream)
{
    const float* feat_l = (const float*)d_in[0];
    const float* feat_r = (const float*)d_in[1];
    const float* disp   = (const float*)d_in[2];
    float* out = (float*)d_out;

    dim3 grid(NSEG * BB * HH);   // 512 blocks: (wseg, b, h); 2 blocks/CU
    dim3 block(512);             // 8 waves; thread = (pixel, channel-octet)
    cost_volume_kernel<<<grid, block, 0, stream>>>(feat_l, feat_r, disp, out);
}